// Round 8
// baseline (250.071 us; speedup 1.0000x reference)
//
#include <hip/hip_runtime.h>
#include <type_traits>

#define S_LEN 2048
#define HID   768
#define NHEAD 12
#define HDIM  64
#define BATCH 4

typedef __attribute__((ext_vector_type(4))) float float4v;
typedef __attribute__((ext_vector_type(8))) short short8;
typedef __attribute__((ext_vector_type(4))) short short4v;
typedef __attribute__((ext_vector_type(2))) int int2v;

__device__ __forceinline__ short f2b(float f) {
  unsigned u = __float_as_uint(f);
  u += 0x7fff + ((u >> 16) & 1);   // RNE
  return (short)(u >> 16);
}

__device__ __forceinline__ unsigned pkbf(float a, float b) {
#if __has_builtin(__builtin_amdgcn_cvt_pk_bf16_f32)
  typedef __attribute__((ext_vector_type(2))) __bf16 bf2;
  bf2 r = __builtin_amdgcn_cvt_pk_bf16_f32(a, b);
  return *(unsigned*)&r;
#else
  return ((unsigned)(unsigned short)f2b(a)) |
         (((unsigned)(unsigned short)f2b(b)) << 16);
#endif
}

__device__ __forceinline__ float fexp2(float x) {
#if __has_builtin(__builtin_amdgcn_exp2f)
  return __builtin_amdgcn_exp2f(x);
#else
  return __expf(x * 0.69314718056f);
#endif
}

// async global->LDS, 16 B per lane; lds base must be wave-uniform
__device__ __forceinline__ void g2l16(const short* g, short* l) {
  __builtin_amdgcn_global_load_lds(
      (const __attribute__((address_space(1))) void*)g,
      (__attribute__((address_space(3))) void*)l, 16, 0, 0);
}

// ---------------- fused pre-pass: cvt x + transpose both weights ----------------
__global__ __launch_bounds__(256) void prepass(const float* __restrict__ x,
                                               const float* __restrict__ w_qkv,
                                               const float* __restrict__ w_out,
                                               short* __restrict__ xb,
                                               short* __restrict__ wqkvT,
                                               short* __restrict__ woutT) {
  __shared__ float tile[64][65];
  const int blk = blockIdx.x;
  if (blk < 3072) {  // cvt: 2048 elems per block
    int i = blk * 2048 + threadIdx.x * 8;
    float4v a = *(const float4v*)&x[i];
    float4v b = *(const float4v*)&x[i + 4];
    short8 o;
#pragma unroll
    for (int j = 0; j < 4; j++) { o[j] = f2b(a[j]); o[j + 4] = f2b(b[j]); }
    *(short8*)&xb[i] = o;
    return;
  }
  const float* W; short* WT; int N_, scaleN, idx;
  if (blk < 3504) { idx = blk - 3072; W = w_qkv; WT = wqkvT; N_ = 3 * HID; scaleN = HID; }
  else            { idx = blk - 3504; W = w_out; WT = woutT; N_ = HID;     scaleN = 0;  }
  const int nblk = N_ / 64;
  const int n0 = (idx % nblk) * 64, k0 = (idx / nblk) * 64;
  const int tx = threadIdx.x & 63, ty = threadIdx.x >> 6;
#pragma unroll
  for (int r = 0; r < 16; r++) {
    int row = r * 4 + ty;
    tile[row][tx] = W[(size_t)(k0 + row) * N_ + n0 + tx];
  }
  __syncthreads();
#pragma unroll
  for (int r = 0; r < 16; r++) {
    int row = r * 4 + ty;
    float sc = (n0 + row < scaleN) ? 0.18033688011f : 1.0f;  // 0.125*log2e
    WT[(size_t)(n0 + row) * HID + k0 + tx] = f2b(tile[tx][row] * sc);
  }
}

// ---------------- m97-style bf16 GEMM: C[MxN] = A[MxK] * Bt[NxK]^T ----------
template <int OUT>
__global__ __launch_bounds__(256) void gemm_bt(const short* __restrict__ A,
                                               const short* __restrict__ Bt,
                                               float* __restrict__ Cf,
                                               short* __restrict__ Cq,
                                               short* __restrict__ vT,
                                               int M, int N, int K) {
  __shared__ __align__(16) short As[128 * 32];
  __shared__ __align__(16) short Bs[128 * 32];
  const int tid = threadIdx.x;
  const int w = tid >> 6, lane = tid & 63;
  const int quad = lane >> 4, lm = lane & 15;
  const int m0 = blockIdx.y * 128, n0 = blockIdx.x * 128;
  const int mo = (w & 1) * 64, no = (w >> 1) * 64;

  float4v acc[4][4];
#pragma unroll
  for (int i = 0; i < 4; i++)
#pragma unroll
    for (int j = 0; j < 4; j++) acc[i][j] = (float4v)0.0f;

  const int srow = w * 32 + (lane >> 2);
  const int scol = (lane & 3) * 8;
  const short* Ag = A + (size_t)(m0 + srow) * K + scol;
  const short* Bg = Bt + (size_t)(n0 + srow) * K + scol;
  short* Al = &As[(w * 32) * 32];
  short* Bl = &Bs[(w * 32) * 32];

  for (int kb = 0; kb < K; kb += 32) {
    g2l16(Ag + kb, Al);
    g2l16(Ag + kb + (size_t)16 * K, Al + 16 * 32);
    g2l16(Bg + kb, Bl);
    g2l16(Bg + kb + (size_t)16 * K, Bl + 16 * 32);
    __syncthreads();

    short8 af[4], bf[4];
#pragma unroll
    for (int i = 0; i < 4; i++)
      af[i] = *(const short8*)&As[(mo + i * 16 + lm) * 32 + quad * 8];
#pragma unroll
    for (int j = 0; j < 4; j++)
      bf[j] = *(const short8*)&Bs[(no + j * 16 + lm) * 32 + quad * 8];
#pragma unroll
    for (int i = 0; i < 4; i++)
#pragma unroll
      for (int j = 0; j < 4; j++)
        acc[i][j] = __builtin_amdgcn_mfma_f32_16x16x32_bf16(af[i], bf[j], acc[i][j], 0, 0, 0);
    __syncthreads();
  }

  if constexpr (OUT == 0) {
#pragma unroll
    for (int i = 0; i < 4; i++)
#pragma unroll
      for (int j = 0; j < 4; j++)
#pragma unroll
        for (int r = 0; r < 4; r++)
          Cf[(size_t)(m0 + mo + i * 16 + quad * 4 + r) * N + n0 + no + j * 16 + lm] =
              acc[i][j][r];
  } else {
    if (n0 >= 2 * HID) {  // V tile -> vT[b][h][d][s]
      const int b = m0 >> 11;
      const int s0 = (m0 & 2047) + mo + quad * 4;
#pragma unroll
      for (int i = 0; i < 4; i++)
#pragma unroll
        for (int j = 0; j < 4; j++) {
          int col = n0 + no + j * 16 + lm - 2 * HID;
          int h = col >> 6, d = col & 63;
          short4v pv;
#pragma unroll
          for (int r = 0; r < 4; r++) pv[r] = f2b(acc[i][j][r]);
          *(short4v*)&vT[((size_t)(b * NHEAD + h) * HDIM + d) * S_LEN + s0 + i * 16] = pv;
        }
    } else {  // Q/K tile -> qk[m][1536]
#pragma unroll
      for (int i = 0; i < 4; i++)
#pragma unroll
        for (int j = 0; j < 4; j++)
#pragma unroll
          for (int r = 0; r < 4; r++)
            Cq[(size_t)(m0 + mo + i * 16 + quad * 4 + r) * (2 * HID) + n0 + no + j * 16 + lm] =
                f2b(acc[i][j][r]);
    }
  }
}

// ---------------- MFMA flash attention, causal, fixed-max softmax ----------------
// Block (bh, a): q-tiles qtA=a (gated), qtB=31-a (always) -> constant 33 tile-computes.
// 46 KB LDS forces exactly 3 blocks/CU (768 blocks = 3*256: balanced residency).
// K/V frags hoisted per kt (shared by both tiles); row-sums via ones-MFMA.
#define PST 72

__global__ __launch_bounds__(256, 3) void attn_mfma(const short* __restrict__ qk,
                                                    const short* __restrict__ vT,
                                                    short* __restrict__ attnout) {
  __shared__ __align__(16) short Qs[128 * PST];     // rows 0..63 = tile A, 64..127 = tile B
  __shared__ __align__(16) short Ks[64 * PST];      // [p][d], p key-permuted
  __shared__ __align__(16) short Vt[64 * PST];      // [d][key]
  __shared__ __align__(16) short Ps[4][16 * PST];   // per-wave [m][key]

  const int tid = threadIdx.x;
  const int w = tid >> 6, lane = tid & 63;
  const int quad = lane >> 4, lm = lane & 15;
  const int bh = blockIdx.x, a = blockIdx.y;
  const int b = bh / NHEAD, h = bh % NHEAD;
  const int qtile[2] = {a, 31 - a};

  // stage both Q tiles
#pragma unroll
  for (int i = 0; i < 4; i++) {
    int flat = i * 256 + tid;
    int row = flat >> 3, c8 = (flat & 7) * 8;
    int grow = qtile[row >> 6] * 64 + (row & 63);
    *(short8*)&Qs[row * PST + c8] =
        *(const short8*)&qk[(size_t)(b * S_LEN + grow) * (2 * HID) + h * HDIM + c8];
  }

  float4v o_acc[2][4], o_sum[2];
#pragma unroll
  for (int t = 0; t < 2; t++) {
    o_sum[t] = (float4v)0.0f;
#pragma unroll
    for (int nt = 0; nt < 4; nt++) o_acc[t][nt] = (float4v)0.0f;
  }

  // all-ones bf16 B-frag for row-sum MFMA
  short8 ones;
#pragma unroll
  for (int i = 0; i < 8; i++) ones[i] = (short)0x3F80;

  const int ktmax = 32 - a;
  short8 kreg[2], vreg[2];

  // pointer-increment prefetch bases (thread-fixed row/col, advance per kt)
  const int p0 = tid >> 3, c8g = (tid & 7) * 8;
  const int key0 = 4 * (p0 & 15) + (p0 >> 4);   // key(p0+32) = key0 + 2
  const short* kp = qk + (size_t)(b * S_LEN) * (2 * HID) + HID + h * HDIM +
                    (size_t)key0 * (2 * HID) + c8g;
  const short* vp = vT + (size_t)(b * NHEAD + h) * HDIM * S_LEN +
                    (size_t)p0 * S_LEN + c8g;
  const size_t KSTEP = (size_t)64 * 2 * HID;

#define PREFETCH()                                        \
  {                                                       \
    kreg[0] = *(const short8*)kp;                         \
    kreg[1] = *(const short8*)(kp + 2 * (2 * HID));       \
    vreg[0] = *(const short8*)vp;                         \
    vreg[1] = *(const short8*)(vp + 32 * S_LEN);          \
    kp += KSTEP; vp += 64;                                \
  }

  PREFETCH();

  for (int kt = 0; kt < ktmax; kt++) {
    __syncthreads();
#pragma unroll
    for (int i = 0; i < 2; i++) {
      int p = p0 + i * 32;
      *(short8*)&Ks[p * PST + c8g] = kreg[i];
      *(short8*)&Vt[p * PST + c8g] = vreg[i];
    }
    __syncthreads();
    if (kt + 1 < ktmax) PREFETCH();

    // K and V fragments once per kt, shared across both q-tiles
    short8 kf[2][4], vf[2][4];
#pragma unroll
    for (int kb = 0; kb < 2; kb++)
#pragma unroll
      for (int nt = 0; nt < 4; nt++) {
        kf[kb][nt] = *(const short8*)&Ks[(nt * 16 + lm) * PST + kb * 32 + quad * 8];
        vf[kb][nt] = *(const short8*)&Vt[(nt * 16 + lm) * PST + kb * 32 + quad * 8];
      }

#pragma unroll
    for (int t = 0; t < 2; t++) {
      if (t == 0 && kt > a) continue;   // tile A done after its diagonal
      float4v s_acc[4];
#pragma unroll
      for (int i = 0; i < 4; i++) s_acc[i] = (float4v)0.0f;
#pragma unroll
      for (int kb = 0; kb < 2; kb++) {
        short8 aq = *(const short8*)&Qs[(t * 64 + w * 16 + lm) * PST + kb * 32 + quad * 8];
#pragma unroll
        for (int nt = 0; nt < 4; nt++)
          s_acc[nt] = __builtin_amdgcn_mfma_f32_16x16x32_bf16(aq, kf[kb][nt], s_acc[nt], 0, 0, 0);
      }

      const bool diag = (kt == qtile[t]);
#pragma unroll
      for (int r = 0; r < 4; r++) {
        float e[4];
#pragma unroll
        for (int nt = 0; nt < 4; nt++) {
          float v = fexp2(s_acc[nt][r]);  // Q pre-scaled by 0.125*log2e
          if (diag && (4 * lm + nt > w * 16 + quad * 4 + r)) v = 0.0f;
          e[nt] = v;
        }
        int2v p2 = {(int)pkbf(e[0], e[1]), (int)pkbf(e[2], e[3])};
        *(int2v*)&Ps[w][(quad * 4 + r) * PST + lm * 4] = p2;  // key = 4*lm+nt
      }

#pragma unroll
      for (int kb = 0; kb < 2; kb++) {
        short8 ap = *(const short8*)&Ps[w][lm * PST + kb * 32 + quad * 8];
#pragma unroll
        for (int nt = 0; nt < 4; nt++)
          o_acc[t][nt] = __builtin_amdgcn_mfma_f32_16x16x32_bf16(ap, vf[kb][nt], o_acc[t][nt], 0, 0, 0);
        // row-sum of P via ones-MFMA (replaces 16 v_adds + final shuffle reduce)
        o_sum[t] = __builtin_amdgcn_mfma_f32_16x16x32_bf16(ap, ones, o_sum[t], 0, 0, 0);
      }
    }
  }

#pragma unroll
  for (int t = 0; t < 2; t++)
#pragma unroll
    for (int r = 0; r < 4; r++) {
      float inv = 1.0f / o_sum[t][r];   // every lane's col holds the full row sum
      int rowg = b * S_LEN + qtile[t] * 64 + w * 16 + quad * 4 + r;
#pragma unroll
      for (int nt = 0; nt < 4; nt++)
        attnout[(size_t)rowg * HID + h * HDIM + nt * 16 + lm] =
            f2b(o_acc[t][nt][r] * inv);
    }
}

extern "C" void kernel_launch(void* const* d_in, const int* in_sizes, int n_in,
                              void* d_out, int out_size, void* d_ws, size_t ws_size,
                              hipStream_t stream) {
  const float* x     = (const float*)d_in[0];
  const float* w_qkv = (const float*)d_in[1];
  const float* w_out = (const float*)d_in[2];
  float* out = (float*)d_out;

  const int M = BATCH * S_LEN;  // 8192
  short* qk     = (short*)d_ws;                       // [8192][1536] bf16
  short* attn   = qk + (size_t)M * 2 * HID;           // [8192][768]  bf16
  short* vT     = attn + (size_t)M * HID;             // [B][NH][64][2048] bf16
  short* xb     = vT + (size_t)M * HID;               // [8192][768]  bf16
  short* wqkvT  = xb + (size_t)M * HID;               // [2304][768]  bf16 (Q rows pre-scaled)
  short* woutT  = wqkvT + (size_t)(3 * HID) * HID;    // [768][768]   bf16

  prepass<<<3648, 256, 0, stream>>>(x, w_qkv, w_out, xb, wqkvT, woutT);

  gemm_bt<1><<<dim3(3 * HID / 128, M / 128), 256, 0, stream>>>(
      xb, wqkvT, nullptr, qk, vT, M, 3 * HID, HID);
  attn_mfma<<<dim3(BATCH * NHEAD, S_LEN / 128), 256, 0, stream>>>(qk, vT, attn);
  gemm_bt<0><<<dim3(HID / 128, M / 128), 256, 0, stream>>>(
      attn, woutT, out, nullptr, nullptr, M, HID, HID);
}

// Round 9
// 199.631 us; speedup vs baseline: 1.2527x; 1.2527x over previous
//
#include <hip/hip_runtime.h>
#include <type_traits>

#define S_LEN 2048
#define HID   768
#define NHEAD 12
#define HDIM  64
#define BATCH 4

typedef __attribute__((ext_vector_type(4))) float float4v;
typedef __attribute__((ext_vector_type(8))) short short8;
typedef __attribute__((ext_vector_type(4))) short short4v;
typedef __attribute__((ext_vector_type(2))) int int2v;

__device__ __forceinline__ short f2b(float f) {
  unsigned u = __float_as_uint(f);
  u += 0x7fff + ((u >> 16) & 1);   // RNE
  return (short)(u >> 16);
}

__device__ __forceinline__ unsigned pkbf(float a, float b) {
#if __has_builtin(__builtin_amdgcn_cvt_pk_bf16_f32)
  typedef __attribute__((ext_vector_type(2))) __bf16 bf2;
  bf2 r = __builtin_amdgcn_cvt_pk_bf16_f32(a, b);
  return *(unsigned*)&r;
#else
  return ((unsigned)(unsigned short)f2b(a)) |
         (((unsigned)(unsigned short)f2b(b)) << 16);
#endif
}

__device__ __forceinline__ float fexp2(float x) {
#if __has_builtin(__builtin_amdgcn_exp2f)
  return __builtin_amdgcn_exp2f(x);
#else
  return __expf(x * 0.69314718056f);
#endif
}

// async global->LDS, 16 B per lane; lds base must be wave-uniform
__device__ __forceinline__ void g2l16(const short* g, short* l) {
  __builtin_amdgcn_global_load_lds(
      (const __attribute__((address_space(1))) void*)g,
      (__attribute__((address_space(3))) void*)l, 16, 0, 0);
}

// ---------------- fused pre-pass: cvt x + transpose both weights ----------------
__global__ __launch_bounds__(256) void prepass(const float* __restrict__ x,
                                               const float* __restrict__ w_qkv,
                                               const float* __restrict__ w_out,
                                               short* __restrict__ xb,
                                               short* __restrict__ wqkvT,
                                               short* __restrict__ woutT) {
  __shared__ float tile[64][65];
  const int blk = blockIdx.x;
  if (blk < 3072) {  // cvt: 2048 elems per block
    int i = blk * 2048 + threadIdx.x * 8;
    float4v a = *(const float4v*)&x[i];
    float4v b = *(const float4v*)&x[i + 4];
    short8 o;
#pragma unroll
    for (int j = 0; j < 4; j++) { o[j] = f2b(a[j]); o[j + 4] = f2b(b[j]); }
    *(short8*)&xb[i] = o;
    return;
  }
  const float* W; short* WT; int N_, scaleN, idx;
  if (blk < 3504) { idx = blk - 3072; W = w_qkv; WT = wqkvT; N_ = 3 * HID; scaleN = HID; }
  else            { idx = blk - 3504; W = w_out; WT = woutT; N_ = HID;     scaleN = 0;  }
  const int nblk = N_ / 64;
  const int n0 = (idx % nblk) * 64, k0 = (idx / nblk) * 64;
  const int tx = threadIdx.x & 63, ty = threadIdx.x >> 6;
#pragma unroll
  for (int r = 0; r < 16; r++) {
    int row = r * 4 + ty;
    tile[row][tx] = W[(size_t)(k0 + row) * N_ + n0 + tx];
  }
  __syncthreads();
#pragma unroll
  for (int r = 0; r < 16; r++) {
    int row = r * 4 + ty;
    float sc = (n0 + row < scaleN) ? 0.18033688011f : 1.0f;  // 0.125*log2e
    WT[(size_t)(n0 + row) * HID + k0 + tx] = f2b(tile[tx][row] * sc);
  }
}

// ---------------- bf16 GEMM: C[MxN] = A[MxK] * Bt[NxK]^T ----------
// 128x128 tile, BK=64 as two BK=32 sub-buffers (keeps [row][32] g2l16 layout),
// halving barrier count vs m97-style BK=32.
template <int OUT>
__global__ __launch_bounds__(256) void gemm_bt(const short* __restrict__ A,
                                               const short* __restrict__ Bt,
                                               float* __restrict__ Cf,
                                               short* __restrict__ Cq,
                                               short* __restrict__ vT,
                                               int M, int N, int K) {
  __shared__ __align__(16) short As[2][128 * 32];
  __shared__ __align__(16) short Bs[2][128 * 32];
  const int tid = threadIdx.x;
  const int w = tid >> 6, lane = tid & 63;
  const int quad = lane >> 4, lm = lane & 15;
  const int m0 = blockIdx.y * 128, n0 = blockIdx.x * 128;
  const int mo = (w & 1) * 64, no = (w >> 1) * 64;

  float4v acc[4][4];
#pragma unroll
  for (int i = 0; i < 4; i++)
#pragma unroll
    for (int j = 0; j < 4; j++) acc[i][j] = (float4v)0.0f;

  const int srow = w * 32 + (lane >> 2);
  const int scol = (lane & 3) * 8;
  const short* Ag = A + (size_t)(m0 + srow) * K + scol;
  const short* Bg = Bt + (size_t)(n0 + srow) * K + scol;

  for (int kb = 0; kb < K; kb += 64) {
#pragma unroll
    for (int s = 0; s < 2; s++) {
      short* Al = &As[s][(w * 32) * 32];
      short* Bl = &Bs[s][(w * 32) * 32];
      g2l16(Ag + kb + s * 32, Al);
      g2l16(Ag + kb + s * 32 + (size_t)16 * K, Al + 16 * 32);
      g2l16(Bg + kb + s * 32, Bl);
      g2l16(Bg + kb + s * 32 + (size_t)16 * K, Bl + 16 * 32);
    }
    __syncthreads();

#pragma unroll
    for (int s = 0; s < 2; s++) {
      short8 af[4], bf[4];
#pragma unroll
      for (int i = 0; i < 4; i++)
        af[i] = *(const short8*)&As[s][(mo + i * 16 + lm) * 32 + quad * 8];
#pragma unroll
      for (int j = 0; j < 4; j++)
        bf[j] = *(const short8*)&Bs[s][(no + j * 16 + lm) * 32 + quad * 8];
#pragma unroll
      for (int i = 0; i < 4; i++)
#pragma unroll
        for (int j = 0; j < 4; j++)
          acc[i][j] = __builtin_amdgcn_mfma_f32_16x16x32_bf16(af[i], bf[j], acc[i][j], 0, 0, 0);
    }
    __syncthreads();
  }

  if constexpr (OUT == 0) {
#pragma unroll
    for (int i = 0; i < 4; i++)
#pragma unroll
      for (int j = 0; j < 4; j++)
#pragma unroll
        for (int r = 0; r < 4; r++)
          Cf[(size_t)(m0 + mo + i * 16 + quad * 4 + r) * N + n0 + no + j * 16 + lm] =
              acc[i][j][r];
  } else {
    if (n0 >= 2 * HID) {  // V tile -> vT[b][h][d][s]
      const int b = m0 >> 11;
      const int s0 = (m0 & 2047) + mo + quad * 4;
#pragma unroll
      for (int i = 0; i < 4; i++)
#pragma unroll
        for (int j = 0; j < 4; j++) {
          int col = n0 + no + j * 16 + lm - 2 * HID;
          int h = col >> 6, d = col & 63;
          short4v pv;
#pragma unroll
          for (int r = 0; r < 4; r++) pv[r] = f2b(acc[i][j][r]);
          *(short4v*)&vT[((size_t)(b * NHEAD + h) * HDIM + d) * S_LEN + s0 + i * 16] = pv;
        }
    } else {  // Q/K tile -> qk[m][1536]
#pragma unroll
      for (int i = 0; i < 4; i++)
#pragma unroll
        for (int j = 0; j < 4; j++)
#pragma unroll
          for (int r = 0; r < 4; r++)
            Cq[(size_t)(m0 + mo + i * 16 + quad * 4 + r) * (2 * HID) + n0 + no + j * 16 + lm] =
                f2b(acc[i][j][r]);
    }
  }
}

// ---------------- MFMA flash attention (round-7 version, verbatim revert) ----
// Narrow feasibility notch (r6/r8 lessons): 46 KB LDS -> exactly 3 blocks/CU
// balanced residency; VGPR must stay ~68 (fragment hoisting spills).
#define PST 72

__global__ __launch_bounds__(256) void attn_mfma(const short* __restrict__ qk,
                                                 const short* __restrict__ vT,
                                                 short* __restrict__ attnout) {
  __shared__ __align__(16) short Qs[128 * PST];     // rows 0..63 = tile A, 64..127 = tile B
  __shared__ __align__(16) short Ks[64 * PST];      // [p][d], p key-permuted
  __shared__ __align__(16) short Vt[64 * PST];      // [d][key]
  __shared__ __align__(16) short Ps[4][16 * PST];   // per-wave [m][key]

  const int tid = threadIdx.x;
  const int w = tid >> 6, lane = tid & 63;
  const int quad = lane >> 4, lm = lane & 15;
  const int bh = blockIdx.x, a = blockIdx.y;
  const int b = bh / NHEAD, h = bh % NHEAD;
  const int qtile[2] = {a, 31 - a};

  const size_t kbase = (size_t)(b * S_LEN) * (2 * HID) + HID + h * HDIM;
  const size_t vbase = (size_t)(b * NHEAD + h) * HDIM * S_LEN;

  // stage both Q tiles
#pragma unroll
  for (int i = 0; i < 4; i++) {
    int flat = i * 256 + tid;
    int row = flat >> 3, c8 = (flat & 7) * 8;
    int grow = qtile[row >> 6] * 64 + (row & 63);
    *(short8*)&Qs[row * PST + c8] =
        *(const short8*)&qk[(size_t)(b * S_LEN + grow) * (2 * HID) + h * HDIM + c8];
  }

  float4v o_acc[2][4];
#pragma unroll
  for (int t = 0; t < 2; t++)
#pragma unroll
    for (int nt = 0; nt < 4; nt++) o_acc[t][nt] = (float4v)0.0f;
  float lsum[2][4];
#pragma unroll
  for (int t = 0; t < 2; t++)
#pragma unroll
    for (int r = 0; r < 4; r++) lsum[t][r] = 0.0f;

  const int ktmax = 32 - a;
  short8 kreg[2], vreg[2];

#define PREFETCH(KT)                                                               \
  {                                                                                \
    _Pragma("unroll") for (int i = 0; i < 2; i++) {                                \
      int flat = i * 256 + tid;                                                    \
      int p = flat >> 3, c8 = (flat & 7) * 8;                                      \
      int key = 4 * (p & 15) + (p >> 4);                                           \
      kreg[i] = *(const short8*)&qk[kbase + (size_t)((KT)*64 + key) * (2*HID) + c8]; \
      vreg[i] = *(const short8*)&vT[vbase + (size_t)p * S_LEN + (KT)*64 + c8];     \
    }                                                                              \
  }

  PREFETCH(0);

  for (int kt = 0; kt < ktmax; kt++) {
    __syncthreads();
#pragma unroll
    for (int i = 0; i < 2; i++) {
      int flat = i * 256 + tid;
      int p = flat >> 3, c8 = (flat & 7) * 8;
      *(short8*)&Ks[p * PST + c8] = kreg[i];
      *(short8*)&Vt[p * PST + c8] = vreg[i];
    }
    __syncthreads();
    if (kt + 1 < ktmax) PREFETCH(kt + 1);

#pragma unroll
    for (int t = 0; t < 2; t++) {
      if (t == 0 && kt > a) continue;   // tile A done after its diagonal
      float4v s_acc[4];
#pragma unroll
      for (int i = 0; i < 4; i++) s_acc[i] = (float4v)0.0f;
#pragma unroll
      for (int kb = 0; kb < 2; kb++) {
        short8 aq = *(const short8*)&Qs[(t * 64 + w * 16 + lm) * PST + kb * 32 + quad * 8];
#pragma unroll
        for (int nt = 0; nt < 4; nt++) {
          short8 bk = *(const short8*)&Ks[(nt * 16 + lm) * PST + kb * 32 + quad * 8];
          s_acc[nt] = __builtin_amdgcn_mfma_f32_16x16x32_bf16(aq, bk, s_acc[nt], 0, 0, 0);
        }
      }

      const bool diag = (kt == qtile[t]);
#pragma unroll
      for (int r = 0; r < 4; r++) {
        float e[4];
#pragma unroll
        for (int nt = 0; nt < 4; nt++) {
          float v = fexp2(s_acc[nt][r]);  // Q pre-scaled by 0.125*log2e
          if (diag && (4 * lm + nt > w * 16 + quad * 4 + r)) v = 0.0f;
          lsum[t][r] += v;
          e[nt] = v;
        }
        int2v p2 = {(int)pkbf(e[0], e[1]), (int)pkbf(e[2], e[3])};
        *(int2v*)&Ps[w][(quad * 4 + r) * PST + lm * 4] = p2;  // key = 4*lm+nt
      }

#pragma unroll
      for (int kb = 0; kb < 2; kb++) {
        short8 ap = *(const short8*)&Ps[w][lm * PST + kb * 32 + quad * 8];
#pragma unroll
        for (int nt = 0; nt < 4; nt++) {
          short8 bv = *(const short8*)&Vt[(nt * 16 + lm) * PST + kb * 32 + quad * 8];
          o_acc[t][nt] = __builtin_amdgcn_mfma_f32_16x16x32_bf16(ap, bv, o_acc[t][nt], 0, 0, 0);
        }
      }
    }
  }

#pragma unroll
  for (int t = 0; t < 2; t++)
#pragma unroll
    for (int r = 0; r < 4; r++) {
#pragma unroll
      for (int off = 1; off < 16; off <<= 1)
        lsum[t][r] += __shfl_xor(lsum[t][r], off, 16);
      float inv = 1.0f / lsum[t][r];
      int rowg = b * S_LEN + qtile[t] * 64 + w * 16 + quad * 4 + r;
#pragma unroll
      for (int nt = 0; nt < 4; nt++)
        attnout[(size_t)rowg * HID + h * HDIM + nt * 16 + lm] =
            f2b(o_acc[t][nt][r] * inv);
    }
}

extern "C" void kernel_launch(void* const* d_in, const int* in_sizes, int n_in,
                              void* d_out, int out_size, void* d_ws, size_t ws_size,
                              hipStream_t stream) {
  const float* x     = (const float*)d_in[0];
  const float* w_qkv = (const float*)d_in[1];
  const float* w_out = (const float*)d_in[2];
  float* out = (float*)d_out;

  const int M = BATCH * S_LEN;  // 8192
  short* qk     = (short*)d_ws;                       // [8192][1536] bf16
  short* attn   = qk + (size_t)M * 2 * HID;           // [8192][768]  bf16
  short* vT     = attn + (size_t)M * HID;             // [B][NH][64][2048] bf16
  short* xb     = vT + (size_t)M * HID;               // [8192][768]  bf16
  short* wqkvT  = xb + (size_t)M * HID;               // [2304][768]  bf16 (Q rows pre-scaled)
  short* woutT  = wqkvT + (size_t)(3 * HID) * HID;    // [768][768]   bf16

  prepass<<<3648, 256, 0, stream>>>(x, w_qkv, w_out, xb, wqkvT, woutT);

  gemm_bt<1><<<dim3(3 * HID / 128, M / 128), 256, 0, stream>>>(
      xb, wqkvT, nullptr, qk, vT, M, 3 * HID, HID);
  attn_mfma<<<dim3(BATCH * NHEAD, S_LEN / 128), 256, 0, stream>>>(qk, vT, attn);
  gemm_bt<0><<<dim3(HID / 128, M / 128), 256, 0, stream>>>(
      attn, woutT, out, nullptr, nullptr, M, HID, HID);
}